// Round 1
// baseline (1135.240 us; speedup 1.0000x reference)
//
#include <hip/hip_runtime.h>
#include <stdint.h>

typedef __attribute__((ext_vector_type(8))) short bf16x8;
typedef __attribute__((ext_vector_type(4))) float f32x4;
typedef __attribute__((ext_vector_type(8))) unsigned short ushort8;

#define DEV __device__ __forceinline__

DEV unsigned short f2bf(float f){
  unsigned u = __float_as_uint(f);
  unsigned r = (u + 0x7FFFu + ((u >> 16) & 1u)) >> 16;
  return (unsigned short)r;
}
DEV float bf2f(unsigned short h){ return __uint_as_float(((unsigned)h) << 16); }

// ---------------- prep kernels ----------------

__global__ void pack_split_k(const float* __restrict__ src, unsigned short* __restrict__ hi,
                             unsigned short* __restrict__ lo, int n){
  int i = blockIdx.x * 256 + threadIdx.x;
  if (i >= n) return;
  float v = src[i];
  unsigned short h = f2bf(v);
  hi[i] = h;
  if (lo) lo[i] = f2bf(v - bf2f(h));
}

__global__ void cnorm_k(const float* __restrict__ cb, float* __restrict__ cn){
  int row = blockIdx.x * 4 + (threadIdx.x >> 6);
  int l = threadIdx.x & 63;
  const float* r = cb + (size_t)row * 768;
  float s = 0.f;
  for (int k = l; k < 768; k += 64){ float v = r[k]; s += v * v; }
  #pragma unroll
  for (int off = 32; off; off >>= 1) s += __shfl_down(s, off);
  if (l == 0) cn[row] = s;
}

// maxpool 2x2 on img (16,2048,64,64) -> X[m=16384][c=2048] split into bf16 hi/lo
__global__ __launch_bounds__(256) void pool_pack_k(const float* __restrict__ img,
    unsigned short* __restrict__ xhi, unsigned short* __restrict__ xlo){
  int blk = blockIdx.x;
  int cblk = blk & 31, h = (blk >> 5) & 31, b = blk >> 10;
  int w = threadIdx.x & 31, cg = threadIdx.x >> 5;
  int m = (b * 32 + h) * 32 + w;
  int c0 = cblk * 64 + cg * 8;
  ushort8 vh, vl;
  #pragma unroll
  for (int j = 0; j < 8; ++j){
    int c = c0 + j;
    const float* p = img + (((size_t)(b * 2048 + c) * 64 + 2 * h) * 64 + 2 * w);
    float2 r0 = *(const float2*)p;
    float2 r1 = *(const float2*)(p + 64);
    float v = fmaxf(fmaxf(r0.x, r0.y), fmaxf(r1.x, r1.y));
    unsigned short hh = f2bf(v);
    vh[j] = hh;
    vl[j] = f2bf(v - bf2f(hh));
  }
  *(ushort8*)(xhi + (size_t)m * 2048 + c0) = vh;
  *(ushort8*)(xlo + (size_t)m * 2048 + c0) = vl;
}

// ---------------- GEMM: C = A * B^T, A[M][K] (row-major), B[N][K] (row-major) ----------------
// 128x128 tile, BK=64, 4 waves, mfma 16x16x32 bf16. LDS source-swizzled (chunk ^= row&7).
// EPI 0: out fp32 (+bias) and optional bf16 hi/lo split.  EPI 1: argmin of bias[n]-2*acc via u64 atomicMin.
// SPLIT: A/B given as hi+lo, accumulate hh+hl+lh.  GATHER: A row r comes from Ahi + gidx[r]*K.
template<int EPI, bool SPLIT, bool GATHER>
__global__ __launch_bounds__(256, 2) void gemm128_k(
    const unsigned short* __restrict__ Ahi, const unsigned short* __restrict__ Alo,
    const unsigned short* __restrict__ Bhi, const unsigned short* __restrict__ Blo,
    int M, int N, int K,
    const int* __restrict__ gidx,
    const float* __restrict__ bias,
    float* __restrict__ outf, unsigned short* __restrict__ outhi, unsigned short* __restrict__ outlo,
    unsigned long long* __restrict__ amin)
{
  (void)M;
  extern __shared__ __align__(16) char smem[];
  const int SZ = 128 * 64 * 2;
  char* sA  = smem;
  char* sB  = smem + SZ;
  char* sAl = smem + 2 * SZ;
  char* sBl = smem + 3 * SZ;

  int tid = threadIdx.x, l = tid & 63, wv = tid >> 6;
  int nt = N >> 7;
  int bm = blockIdx.x / nt, bn = blockIdx.x - bm * nt;
  int m0 = bm << 7, n0 = bn << 7;

  // staging addressing: round i, wave wv, lane l -> tile row r, 16B chunk (l&7),
  // source chunk pre-swizzled so that linear LDS + XOR-read is conflict-reduced.
  long long aoff[4], boff[4];
  #pragma unroll
  for (int i = 0; i < 4; ++i){
    int r = i * 32 + wv * 8 + (l >> 3);
    int cc = (l & 7) ^ (r & 7);
    long long arow;
    if constexpr (GATHER) arow = (long long)gidx[m0 + r] * K;
    else                  arow = (long long)(m0 + r) * K;
    aoff[i] = arow + cc * 8;
    boff[i] = (long long)(n0 + r) * K + cc * 8;
  }

  f32x4 acc[4][4];
  f32x4 zero = {0.f, 0.f, 0.f, 0.f};
  #pragma unroll
  for (int i = 0; i < 4; ++i)
    #pragma unroll
    for (int j = 0; j < 4; ++j) acc[i][j] = zero;

  int wm = (wv >> 1) * 64, wn = (wv & 1) * 64;

  for (int kt = 0; kt < (K >> 6); ++kt){
    int k0 = kt << 6;
    #pragma unroll
    for (int i = 0; i < 4; ++i){
      __builtin_amdgcn_global_load_lds(
        (const __attribute__((address_space(1))) void*)(Ahi + aoff[i] + k0),
        (__attribute__((address_space(3))) void*)(sA + i * 4096 + wv * 1024), 16, 0, 0);
      __builtin_amdgcn_global_load_lds(
        (const __attribute__((address_space(1))) void*)(Bhi + boff[i] + k0),
        (__attribute__((address_space(3))) void*)(sB + i * 4096 + wv * 1024), 16, 0, 0);
      if constexpr (SPLIT){
        __builtin_amdgcn_global_load_lds(
          (const __attribute__((address_space(1))) void*)(Alo + aoff[i] + k0),
          (__attribute__((address_space(3))) void*)(sAl + i * 4096 + wv * 1024), 16, 0, 0);
        __builtin_amdgcn_global_load_lds(
          (const __attribute__((address_space(1))) void*)(Blo + boff[i] + k0),
          (__attribute__((address_space(3))) void*)(sBl + i * 4096 + wv * 1024), 16, 0, 0);
      }
    }
    __syncthreads();
    #pragma unroll
    for (int kk = 0; kk < 2; ++kk){
      bf16x8 ah[4], bh[4], al[4], bl[4];
      #pragma unroll
      for (int i = 0; i < 4; ++i){
        int ra = wm + i * 16 + (l & 15);
        int ba = ra * 128 + ((kk * 64 + (l >> 4) * 16) ^ ((ra & 7) << 4));
        ah[i] = *(const bf16x8*)(sA + ba);
        if constexpr (SPLIT) al[i] = *(const bf16x8*)(sAl + ba);
        int rb = wn + i * 16 + (l & 15);
        int bb = rb * 128 + ((kk * 64 + (l >> 4) * 16) ^ ((rb & 7) << 4));
        bh[i] = *(const bf16x8*)(sB + bb);
        if constexpr (SPLIT) bl[i] = *(const bf16x8*)(sBl + bb);
      }
      #pragma unroll
      for (int i = 0; i < 4; ++i)
        #pragma unroll
        for (int j = 0; j < 4; ++j){
          acc[i][j] = __builtin_amdgcn_mfma_f32_16x16x32_bf16(ah[i], bh[j], acc[i][j], 0, 0, 0);
          if constexpr (SPLIT){
            acc[i][j] = __builtin_amdgcn_mfma_f32_16x16x32_bf16(ah[i], bl[j], acc[i][j], 0, 0, 0);
            acc[i][j] = __builtin_amdgcn_mfma_f32_16x16x32_bf16(al[i], bh[j], acc[i][j], 0, 0, 0);
          }
        }
    }
    __syncthreads();
  }

  if constexpr (EPI == 0){
    #pragma unroll
    for (int i = 0; i < 4; ++i){
      int mrow = m0 + wm + i * 16 + ((l >> 4) << 2);
      #pragma unroll
      for (int j = 0; j < 4; ++j){
        int n = n0 + wn + j * 16 + (l & 15);
        float bv = bias[n];
        #pragma unroll
        for (int q = 0; q < 4; ++q){
          float v = acc[i][j][q] + bv;
          size_t o = (size_t)(mrow + q) * N + n;
          outf[o] = v;
          if (outhi){
            unsigned short h = f2bf(v);
            outhi[o] = h;
            outlo[o] = f2bf(v - bf2f(h));
          }
        }
      }
    }
  } else {
    // argmin epilogue: score = |c_n|^2 - 2*f.c_n ; pack (orderable, n) -> u64 atomicMin
    #pragma unroll
    for (int i = 0; i < 4; ++i){
      #pragma unroll
      for (int q = 0; q < 4; ++q){
        int mrow = m0 + wm + i * 16 + ((l >> 4) << 2) + q;
        unsigned long long best = ~0ull;
        #pragma unroll
        for (int j = 0; j < 4; ++j){
          int n = n0 + wn + j * 16 + (l & 15);
          float s = bias[n] - 2.0f * acc[i][j][q];
          unsigned u = __float_as_uint(s);
          u = (u & 0x80000000u) ? ~u : (u | 0x80000000u);
          unsigned long long pk = ((unsigned long long)u << 32) | (unsigned)n;
          best = pk < best ? pk : best;
        }
        #pragma unroll
        for (int off = 1; off < 16; off <<= 1){
          unsigned hw2 = __shfl_xor((unsigned)(best >> 32), off);
          unsigned lw2 = __shfl_xor((unsigned)(best & 0xffffffffu), off);
          unsigned long long ob = (((unsigned long long)hw2) << 32) | lw2;
          best = ob < best ? ob : best;
        }
        if ((l & 15) == 0) atomicMin(&amin[mrow], best);
      }
    }
  }
}

__global__ void unpack_idx_k(const unsigned long long* __restrict__ am, int* __restrict__ ix){
  int i = blockIdx.x * 256 + threadIdx.x;
  ix[i] = (int)(unsigned)(am[i] & 0xffffffffull);
}

// ---------------- fused epilogue: gate+softmax+mask+posenc+LN, writes out/vm/labels ----------------
__global__ __launch_bounds__(256) void epilogue_k(
  const float* __restrict__ emb, const float* __restrict__ xq,
  const int* __restrict__ idx, const int* __restrict__ vis_hw,
  const int* __restrict__ tmp_pos_p, const float* __restrict__ bern,
  const float* __restrict__ gate_w, const float* __restrict__ gate_b,
  const float* __restrict__ ln_g, const float* __restrict__ ln_b,
  const float* __restrict__ mask_emb,
  float* __restrict__ out)
{
  __shared__ float red[8];
  int m = blockIdx.x;
  int b = m >> 10, hw = m & 1023, h = hw >> 5, w = hw & 31;
  int tid = threadIdx.x;
  int imh = vis_hw[2 * b], imw = vis_hw[2 * b + 1];
  bool hvis = (h * 32 < imh), wvis = (w * 32 < imw);
  bool vis = hvis && wvis;
  int tp = tmp_pos_p[0];
  int th = tp >> 5, tw = tp & 31;
  bool vist = (th * 32 < imh) && (tw * 32 < imw);
  float tl = vist ? (float)idx[b * 1024 + tp] : -100.0f;
  float ind = vis ? (float)idx[m] : -100.0f;
  float mi = (vis && ind == tl) ? bern[b] : 0.0f;   // 0.0 or 1.0

  const float* er = emb + (size_t)m * 768;
  const float* xr = xq + (size_t)m * 768;
  float e3[3], x3[3];
  float s0 = 0.f, s1 = 0.f;
  #pragma unroll
  for (int j = 0; j < 3; ++j){
    int c = tid + j * 256;
    float e = er[c], x = xr[c];
    e3[j] = e; x3[j] = x;
    s0 += e * gate_w[c] + x * gate_w[768 + c];
    s1 += e * gate_w[1536 + c] + x * gate_w[1536 + 768 + c];
  }
  #pragma unroll
  for (int off = 32; off; off >>= 1){ s0 += __shfl_down(s0, off); s1 += __shfl_down(s1, off); }
  if ((tid & 63) == 0){ red[tid >> 6] = s0; red[4 + (tid >> 6)] = s1; }
  __syncthreads();
  s0 = red[0] + red[1] + red[2] + red[3] + gate_b[0];
  s1 = red[4] + red[5] + red[6] + red[7] + gate_b[1];
  __syncthreads();
  float mx = fmaxf(s0, s1);
  float p0 = expf(s0 - mx), p1 = expf(s1 - mx);
  float inv = 1.0f / (p0 + p1);
  p0 *= inv; p1 *= inv;

  int Hv = (imh + 31) >> 5, Wv = (imw + 31) >> 5;
  const float TWOPI = 6.283185307179586f;
  float yemb = wvis ? (fminf((float)(h + 1), (float)Hv) / ((float)Hv + 1e-6f)) * TWOPI : 0.0f;
  float xemb = hvis ? (fminf((float)(w + 1), (float)Wv) / ((float)Wv + 1e-6f)) * TWOPI : 0.0f;
  const float L2T = 0.06920684987139486f;  // log2(10000)/192

  float fv[3];
  float sum = 0.f, ssq = 0.f;
  #pragma unroll
  for (int j = 0; j < 3; ++j){
    int c = tid + j * 256;
    float f = e3[j] * p0 + x3[j] * p1;
    f = f * (1.0f - mi) + mask_emb[c] * mi;
    float pc;
    if (c < 384){
      int i = c >> 1;
      float arg = yemb * exp2f(-(float)i * L2T);
      pc = (c & 1) ? cosf(arg) : sinf(arg);
    } else {
      int i = (c - 384) >> 1;
      float arg = xemb * exp2f(-(float)i * L2T);
      pc = (c & 1) ? cosf(arg) : sinf(arg);
    }
    f += pc;
    fv[j] = f;
    sum += f; ssq += f * f;
  }
  #pragma unroll
  for (int off = 32; off; off >>= 1){ sum += __shfl_down(sum, off); ssq += __shfl_down(ssq, off); }
  if ((tid & 63) == 0){ red[tid >> 6] = sum; red[4 + (tid >> 6)] = ssq; }
  __syncthreads();
  sum = red[0] + red[1] + red[2] + red[3];
  ssq = red[4] + red[5] + red[6] + red[7];
  float mean = sum * (1.0f / 768.0f);
  float var = ssq * (1.0f / 768.0f) - mean * mean;
  float rstd = rsqrtf(var + 1e-5f);
  float* orow = out + (size_t)m * 768;
  #pragma unroll
  for (int j = 0; j < 3; ++j){
    int c = tid + j * 256;
    orow[c] = (fv[j] - mean) * rstd * ln_g[c] + ln_b[c];
  }
  if (tid == 0){
    out[12582912 + m]         = vis ? 1.0f : 0.0f;                 // vm_out
    out[12582912 + 16384 + m] = (mi != 0.0f) ? ind : -100.0f;      // labels
  }
}

// ---------------- launcher ----------------
extern "C" void kernel_launch(void* const* d_in, const int* in_sizes, int n_in,
                              void* d_out, int out_size, void* d_ws, size_t ws_size,
                              hipStream_t stream){
  (void)in_sizes; (void)n_in; (void)out_size;
  const float* img     = (const float*)d_in[0];
  const int*   vishw   = (const int*)d_in[1];
  const int*   tmp_pos = (const int*)d_in[2];
  const float* bern    = (const float*)d_in[3];
  const float* conv_w  = (const float*)d_in[4];
  const float* conv_b  = (const float*)d_in[5];
  const float* codebook= (const float*)d_in[6];
  const float* pos_w   = (const float*)d_in[7];
  const float* pos_b   = (const float*)d_in[8];
  const float* gate_w  = (const float*)d_in[9];
  const float* gate_b  = (const float*)d_in[10];
  const float* ln_g    = (const float*)d_in[11];
  const float* ln_b    = (const float*)d_in[12];
  const float* mask_emb= (const float*)d_in[13];
  float* out = (float*)d_out;

  char* wsp = (char*)d_ws;
  size_t off = 0;
  auto take = [&](size_t bytes)->char*{
    char* q = wsp + off; off += (bytes + 255) & ~(size_t)255; return q;
  };
  unsigned short* Xhi  = (unsigned short*)take(16384ull * 2048 * 2);
  unsigned short* Xlo  = (unsigned short*)take(16384ull * 2048 * 2);
  unsigned short* Whi  = (unsigned short*)take(768ull * 2048 * 2);
  unsigned short* Wlo  = (unsigned short*)take(768ull * 2048 * 2);
  unsigned short* CBhi = (unsigned short*)take(2048ull * 768 * 2);
  unsigned short* CBlo = (unsigned short*)take(2048ull * 768 * 2);
  unsigned short* PWhi = (unsigned short*)take(768ull * 768 * 2);
  float*          cnm  = (float*)take(2048 * 4);
  float*          flat = (float*)take(16384ull * 768 * 4);
  unsigned short* Fhi  = (unsigned short*)take(16384ull * 768 * 2);
  unsigned short* Flo  = (unsigned short*)take(16384ull * 768 * 2);
  unsigned long long* amin = (unsigned long long*)take(16384ull * 8);
  int*            idx  = (int*)take(16384 * 4);
  // X region is dead after the conv GEMM; reuse it for emb (50.3 MB <= 67.1 MB)
  float* emb = (float*)Xhi;

  hipMemsetAsync(amin, 0xFF, 16384ull * 8, stream);

  pack_split_k<<<(1572864 + 255) / 256, 256, 0, stream>>>(conv_w, Whi, Wlo, 1572864);
  pack_split_k<<<(1572864 + 255) / 256, 256, 0, stream>>>(codebook, CBhi, CBlo, 1572864);
  pack_split_k<<<(589824 + 255) / 256, 256, 0, stream>>>(pos_w, PWhi, nullptr, 589824);
  cnorm_k<<<512, 256, 0, stream>>>(codebook, cnm);
  pool_pack_k<<<16384, 256, 0, stream>>>(img, Xhi, Xlo);

  // conv: flat[16384][768] = X * W^T (split precision), also emit bf16 hi/lo of flat
  gemm128_k<0, true, false><<<128 * 6, 256, 65536, stream>>>(
      Xhi, Xlo, Whi, Wlo, 16384, 768, 2048, nullptr, conv_b, flat, Fhi, Flo, nullptr);

  // d2 scores + argmin: score[m][n] = |c_n|^2 - 2 * flat.c_n   (split precision)
  gemm128_k<1, true, false><<<128 * 16, 256, 65536, stream>>>(
      Fhi, Flo, CBhi, CBlo, 16384, 2048, 768, nullptr, cnm, nullptr, nullptr, nullptr, amin);

  unpack_idx_k<<<64, 256, 0, stream>>>(amin, idx);

  // emb[16384][768] = codebook[idx] * pos_w^T + pos_b   (bf16 single precision, gathered A)
  gemm128_k<0, false, true><<<128 * 6, 256, 32768, stream>>>(
      CBhi, nullptr, PWhi, nullptr, 16384, 768, 768, idx, pos_b, emb, nullptr, nullptr, nullptr);

  epilogue_k<<<16384, 256, 0, stream>>>(emb, flat, idx, vishw, tmp_pos, bern,
                                        gate_w, gate_b, ln_g, ln_b, mask_emb, out);
}